// Round 17
// baseline (106.401 us; speedup 1.0000x reference)
//
#include <hip/hip_runtime.h>
#include <hip/hip_bf16.h>

// Problem constants
#define FIN 250
#define NROWS 129024               // 2048*63
#define NT 8                       // tiles per WAVE
#define NBLK 252                   // 252 blocks x 4 waves = 1008 wave-slots
#define NWAVES 1008                // tile = wave_id + i*NWAVES ; 1008*8 = 8064 tiles

typedef short short8 __attribute__((ext_vector_type(8)));
typedef float f32x4 __attribute__((ext_vector_type(4)));

__device__ __forceinline__ short f2bf(float f) {
    __bf16 b = (__bf16)f;
    return __builtin_bit_cast(short, b);
}

#define WAITV(n) asm volatile("s_waitcnt vmcnt(" #n ")" ::: "memory")
#define WAITL    asm volatile("s_waitcnt lgkmcnt(0)" ::: "memory")
#define SCHEDF   __builtin_amdgcn_sched_barrier(0)

// LDS map: [0,131072) W^T swizzled image (shared, read-only after prologue)
//          [131072 + wv*8192, +8192) per-wave private afrag buffer
#define AFR_BASE 131072

// 16 coalesced 1KB register loads for one wave-private 16-row tile.
// Per-lane addr = rowbase + lane*16; overrun past byte 1000 lands in the next row
// (in-bounds, feeds k>=250 pad slots that multiply zeroed W rows); the very last
// row is redirected to the 1024B zero-padded xlast copy.
__device__ __forceinline__ void load_tile16(uint4 (&lb)[16], const float* __restrict__ x,
                                            const float* __restrict__ xlast,
                                            int tile, int lane) {
    #pragma unroll
    for (int rr = 0; rr < 16; ++rr) {
        int grow = tile * 16 + rr;
        const char* g = (grow == NROWS - 1) ? (const char*)xlast
                                            : (const char*)x + (size_t)grow * 1000u;
        lb[rr] = *(const uint4*)(g + lane * 16);
    }
}

// MFMA + scatter-store for one col-half (8 nf frags). A-frags from wave-private LDS.
__device__ __forceinline__ void mfma_half(const char* afr, const char* wt,
                                          float* __restrict__ out,
                                          int tile, int half, int m, int kg,
                                          unsigned bswz, const float (&bcol)[16]) {
    f32x4 acc[8];
    #pragma unroll
    for (int nf = 0; nf < 8; ++nf) {
        float b = bcol[half * 8 + nf];
        acc[nf] = (f32x4){b, b, b, b};
    }
    const unsigned chbase = (unsigned)(half * 128) * 512u;
    #pragma unroll
    for (int kk = 0; kk < 8; ++kk) {
        short8 af = *(const short8*)(afr + kk * 1024 + kg * 256 + ((m ^ kk) * 16));
        #pragma unroll
        for (int nf = 0; nf < 8; ++nf) {
            unsigned off = chbase + (unsigned)(nf * 16 + m) * 512u
                         + (((unsigned)(kk * 64 + kg * 16)) ^ bswz);
            short8 bf = *(const short8*)(wt + off);
            acc[nf] = __builtin_amdgcn_mfma_f32_16x16x32_bf16(af, bf, acc[nf], 0, 0, 0);
        }
    }
    // C/D layout: col = lane&15 (=m), row = kg*4 + j  -> 32 store_dword per half
    unsigned obase = ((unsigned)tile * 16 + (unsigned)kg * 4) * FIN
                   + (unsigned)(half * 128 + m);
    #pragma unroll
    for (int nf = 0; nf < 8; ++nf) {
        if (half == 0 || nf < 7 || m < 10) {   // mask cols 250..255 (exec-masked)
            #pragma unroll
            for (int j = 0; j < 4; ++j)
                out[obase + (unsigned)(j * FIN) + (unsigned)(nf * 16)] = acc[nf][j];
        }
    }
}

// Pre-kernel: SWIZZLED W^T bf16 image [c(256)][k(256, k-pairs packed)], 512B/row,
// off = (c<<9) + ((4kp) ^ ((c&7)<<4)), zero-padded; plus padded last-x-row copy.
__global__ void __launch_bounds__(256)
wt_prep(const float* __restrict__ W, const float* __restrict__ x,
        unsigned* __restrict__ Wt, float* __restrict__ xlast) {
    int i = blockIdx.x * 256 + threadIdx.x;     // 128 blocks x 256 = 32768 words
    unsigned c  = (unsigned)i & 255u;
    unsigned kp = (unsigned)i >> 8;             // 0..127
    unsigned k0 = 2u * kp;
    unsigned lo = 0u, hi = 0u;
    if (c < FIN) {
        if (k0 < FIN)      lo = (unsigned)(unsigned short)f2bf(W[k0 * FIN + c]);
        if (k0 + 1u < FIN) hi = (unsigned)(unsigned short)f2bf(W[(k0 + 1u) * FIN + c]);
    }
    unsigned off = (c << 9) + ((4u * kp) ^ ((c & 7u) << 4));
    *(unsigned*)((char*)Wt + off) = lo | (hi << 16);
    if (blockIdx.x == 0) {
        int t = threadIdx.x;                    // 256 floats = 1024 B
        xlast[t] = (t < FIN) ? x[(size_t)(NROWS - 1) * FIN + t] : 0.f;
    }
}

// BARRIER-FREE steady state: W^T in shared LDS (read-only), each wave fully
// independent: reg-staged coalesced loads -> wave-private afrag -> MFMA -> stores.
// The only inter-wave coupling is the HBM pipe itself.
__global__ void __launch_bounds__(256, 1)
gat_gemm(const float* __restrict__ x, const unsigned* __restrict__ Wt,
         const float* __restrict__ xlast, const float* __restrict__ bias,
         float* __restrict__ out)
{
    __shared__ __align__(16) char lds[163840];   // 128K wt + 4 x 8K afrag = 160 KiB

    const int tid  = threadIdx.x;
    const int lane = tid & 63;
    const int wv   = tid >> 6;        // 0..3
    const int m    = lane & 15;
    const int kg   = lane >> 4;

    // ---- prologue: stage swizzled W^T image (L2/L3-hot); ONLY barrier here ----
    {
        const uint4* s4 = (const uint4*)Wt;
        uint4* d4 = (uint4*)lds;
        for (int i = tid; i < 8192; i += 256) d4[i] = s4[i];
    }
    __syncthreads();                  // also drains vmcnt/lgkm: clean slate

    const unsigned bswz = ((unsigned)(m & 7)) << 4;
    float bcol[16];
    #pragma unroll
    for (int nf = 0; nf < 16; ++nf) {
        int c = nf * 16 + m;          // nf<8: half0 cols; nf>=8: half1 cols
        bcol[nf] = (c < FIN) ? bias[c] : 0.f;
    }

    char* const afr = lds + AFR_BASE + wv * 8192;   // wave-private
    // repack writer decomposition: lane holds floats k=4*lane..4*lane+3 of each row
    const int wkk   = lane >> 3;
    const int wkg   = (lane >> 1) & 3;
    const int whalf = lane & 1;
    const unsigned wroff = (unsigned)(wkk * 1024 + wkg * 256 + whalf * 8);

    WAITV(0); SCHEDF;                 // bias loads drained: clean per-wave ledger

    const int w0 = blockIdx.x * 4 + wv;   // wave-slot 0..1007
    uint4 lb[16];
    load_tile16(lb, x, xlast, w0, lane);

    #pragma unroll 1
    for (int i = 0; i < NT; ++i) {
        const int t = w0 + i * NWAVES;
        // Per-wave ledger at this point: [stores_h0(i-1)32, loads(t)16,
        // stores_h1(i-1)32]. WAITV(32) retires stores_h0 + loads (in-order).
        if (i == 0) { WAITV(0); } else { WAITV(32); }
        SCHEDF;

        // ---- convert + repack 16 rows from registers -> wave-private afrag ----
        #pragma unroll
        for (int rr = 0; rr < 16; ++rr) {
            float v0 = __builtin_bit_cast(float, lb[rr].x);
            float v1 = __builtin_bit_cast(float, lb[rr].y);
            float v2 = __builtin_bit_cast(float, lb[rr].z);
            float v3 = __builtin_bit_cast(float, lb[rr].w);
            unsigned lo = (unsigned)(unsigned short)f2bf(v0)
                        | ((unsigned)(unsigned short)f2bf(v1) << 16);
            unsigned hi = (unsigned)(unsigned short)f2bf(v2)
                        | ((unsigned)(unsigned short)f2bf(v3) << 16);
            *(uint2*)(afr + wroff + (unsigned)(((rr ^ wkk) * 16))) = make_uint2(lo, hi);
        }
        SCHEDF;
        WAITL;                        // my ds_writes done (wave-private: no barrier)
        SCHEDF;

        mfma_half(afr, lds, out, t, 0, m, kg, bswz, bcol);   // half0 + 32 stores
        // lb regs freed at repack; issue next tile's loads under half1's compute
        if (i + 1 < NT) load_tile16(lb, x, xlast, t + NWAVES, lane);
        SCHEDF;
        mfma_half(afr, lds, out, t, 1, m, kg, bswz, bcol);   // half1 + 32 stores
    }
}

// 63-node GAT attention over rows 0..62 of out (holding h+bias). Exact: uniform
// logit shifts cancel in softmax and sum(alpha)=1 folds the bias through the mix.
__global__ void __launch_bounds__(1024, 1)
gat_attn(const float* __restrict__ att_src, const float* __restrict__ att_dst,
         float* __restrict__ out)
{
    __shared__ float hs[63 * 252];
    __shared__ float asrc[64], adst[64];
    __shared__ float alpha[63 * 64];

    const int tid = threadIdx.x;

    for (int idx = tid; idx < 63 * FIN; idx += 1024) {
        int r = idx / FIN, f = idx - r * FIN;
        hs[r * 252 + f] = out[idx];
    }
    __syncthreads();

    {   // logits: 16 threads per row, shfl-reduce
        int r = tid >> 4, t = tid & 15;
        float s1 = 0.f, s2 = 0.f;
        if (r < 63) {
            for (int k = t; k < FIN; k += 16) {
                float h = hs[r * 252 + k];
                s1 += h * att_src[k];
                s2 += h * att_dst[k];
            }
        }
        #pragma unroll
        for (int o = 8; o >= 1; o >>= 1) {
            s1 += __shfl_xor(s1, o, 16);
            s2 += __shfl_xor(s2, o, 16);
        }
        if (r < 63 && t == 0) { asrc[r] = s1; adst[r] = s2; }
    }
    __syncthreads();

    {   // softmax per dst row: 16 threads per row
        int d = tid >> 4, t = tid & 15;
        if (d < 63) {
            float ad = adst[d];
            float e_[4];
            float mx = -1e30f;
            #pragma unroll
            for (int q = 0; q < 4; ++q) {
                int sdx = t + q * 16;
                float e = -1e30f;
                if (sdx < 63) {
                    e = asrc[sdx] + ad;
                    e = e > 0.f ? e : 0.2f * e;     // leaky_relu slope 0.2
                }
                e_[q] = e;
                mx = fmaxf(mx, e);
            }
            #pragma unroll
            for (int o = 8; o >= 1; o >>= 1) mx = fmaxf(mx, __shfl_xor(mx, o, 16));
            float den = 0.f;
            #pragma unroll
            for (int q = 0; q < 4; ++q) {
                int sdx = t + q * 16;
                float ex = (sdx < 63) ? __expf(e_[q] - mx) : 0.f;
                e_[q] = ex;
                den += ex;
            }
            #pragma unroll
            for (int o = 8; o >= 1; o >>= 1) den += __shfl_xor(den, o, 16);
            float rd = 1.f / den;
            #pragma unroll
            for (int q = 0; q < 4; ++q) {
                int sdx = t + q * 16;
                if (sdx < 63) alpha[d * 64 + sdx] = e_[q] * rd;
            }
        }
    }
    __syncthreads();

    for (int idx = tid; idx < 63 * FIN; idx += 1024) {
        int d = idx / FIN, f = idx - d * FIN;
        float v = 0.f;
        for (int sdx = 0; sdx < 63; ++sdx)
            v += alpha[d * 64 + sdx] * hs[sdx * 252 + f];
        out[idx] = v;
    }
}

extern "C" void kernel_launch(void* const* d_in, const int* in_sizes, int n_in,
                              void* d_out, int out_size, void* d_ws, size_t ws_size,
                              hipStream_t stream) {
    (void)in_sizes; (void)n_in; (void)ws_size; (void)out_size;
    const float* x        = (const float*)d_in[0];
    const float* W        = (const float*)d_in[1];
    const float* att_src  = (const float*)d_in[2];
    const float* att_dst  = (const float*)d_in[3];
    const float* bias     = (const float*)d_in[4];
    float* out            = (float*)d_out;
    unsigned* Wt          = (unsigned*)d_ws;                       // 128 KiB image
    float* xlast          = (float*)((char*)d_ws + 131072);        // 1 KiB padded row

    wt_prep<<<128, 256, 0, stream>>>(W, x, Wt, xlast);
    gat_gemm<<<NBLK, 256, 0, stream>>>(x, Wt, xlast, bias, out);
    gat_attn<<<1, 1024, 0, stream>>>(att_src, att_dst, out);
}